// Round 1
// baseline (712.676 us; speedup 1.0000x reference)
//
#include <hip/hip_runtime.h>

// ---------------------------------------------------------------------------
// ROIAwareGCN: 3x GCNConv (CSR-gather, no atomics in hot path) + mean-pool + MLP
// All fp32. CSR built on-device every launch (same work per call).
// ---------------------------------------------------------------------------

__global__ void k_deg(const int* __restrict__ dst, int* __restrict__ cnt, int E) {
    int e = blockIdx.x * blockDim.x + threadIdx.x;
    if (e < E) atomicAdd(&cnt[dst[e]], 1);
}

__global__ void k_dinv(const int* __restrict__ cnt, float* __restrict__ dinv, int n) {
    int i = blockIdx.x * blockDim.x + threadIdx.x;
    if (i < n) dinv[i] = rsqrtf((float)(cnt[i] + 1));  // +1 for self-loop; deg >= 1 always
}

// Single-block exclusive scan over cnt -> rowptr (n+1 entries).
// 4096 elems/chunk, wave-shuffle scans, 4 barriers per chunk (~13 chunks).
__global__ __launch_bounds__(1024) void k_scan(const int* __restrict__ cnt,
                                               int* __restrict__ rowptr, int n) {
    __shared__ int wsum[16];
    __shared__ int carry_s;
    int tid = threadIdx.x;
    int lane = tid & 63;
    int wid = tid >> 6;
    if (tid == 0) carry_s = 0;
    __syncthreads();
    for (int base = 0; base < n; base += 4096) {
        int i0 = base + tid * 4;
        int v[4];
#pragma unroll
        for (int j = 0; j < 4; j++) v[j] = (i0 + j < n) ? cnt[i0 + j] : 0;
        int s0 = v[0], s1 = s0 + v[1], s2 = s1 + v[2], s3 = s2 + v[3];
        int ts = s3;
        int sc = ts;  // wave-inclusive scan of per-thread sums
#pragma unroll
        for (int d = 1; d < 64; d <<= 1) {
            int o = __shfl_up(sc, d);
            if (lane >= d) sc += o;
        }
        if (lane == 63) wsum[wid] = sc;
        __syncthreads();
        if (wid == 0) {
            int v2 = (lane < 16) ? wsum[lane] : 0;
            int sc2 = v2;
#pragma unroll
            for (int d = 1; d < 16; d <<= 1) {
                int o = __shfl_up(sc2, d);
                if (lane >= d) sc2 += o;
            }
            if (lane < 16) wsum[lane] = sc2;
        }
        __syncthreads();
        int waveoff = (wid > 0) ? wsum[wid - 1] : 0;
        int throff = carry_s + waveoff + (sc - ts);  // exclusive offset of this thread's first elem
#pragma unroll
        for (int j = 0; j < 4; j++) {
            int idx = i0 + j;
            int pre = (j == 0) ? 0 : (j == 1 ? s0 : (j == 2 ? s1 : s2));
            if (idx < n) rowptr[idx] = throff + pre;
        }
        __syncthreads();
        if (tid == 0) carry_s += wsum[15];
        __syncthreads();
    }
    if (threadIdx.x == 0) rowptr[n] = carry_s;
}

__global__ void k_csr(const int* __restrict__ src, const int* __restrict__ dst,
                      const int* __restrict__ rowptr, int* __restrict__ fill,
                      const float* __restrict__ dinv, int* __restrict__ col,
                      float* __restrict__ wgt, int E) {
    int e = blockIdx.x * blockDim.x + threadIdx.x;
    if (e >= E) return;
    int s = src[e], d = dst[e];
    int pos = rowptr[d] + atomicAdd(&fill[d], 1);
    col[pos] = s;
    wgt[pos] = dinv[s] * dinv[d];
}

// Tiled fp32 GEMM: C[n][BN] = A[n][128] @ W[128][BN]. BM=64 rows/block, BK=32.
// Each thread: 4 rows x 8 cols. blockDim = BN*2 (256 for BN=128, 128 for BN=64).
template <int BN>
__global__ __launch_bounds__(BN * 2) void k_gemm(const float* __restrict__ A,
                                                 const float* __restrict__ W,
                                                 float* __restrict__ C, int n) {
    constexpr int K = 128;
    constexpr int BM = 64;
    constexpr int BK = 32;
    __shared__ float As[BK][BM + 4];  // +4 pad: 16B-aligned rows, conflict-free writes
    __shared__ float Ws[BK][BN];
    int t = threadIdx.x;
    int tx = t % (BN / 8);
    int ty = t / (BN / 8);  // 0..15
    int row0 = blockIdx.x * BM;
    float acc[4][8];
#pragma unroll
    for (int i = 0; i < 4; i++)
#pragma unroll
        for (int j = 0; j < 8; j++) acc[i][j] = 0.f;

    for (int k0 = 0; k0 < K; k0 += BK) {
        // A tile (transposed into LDS): As[k][m] = A[row0+m][k0+k]
        {
            int lm = t % BM;
            constexpr int nk = (BN * 2) / BM;   // 4 or 2
            constexpr int kper = BK / nk;       // 8 or 16
            int kq = t / BM;
            int row = row0 + lm;
            if (row < n) {
                const float* ap = A + (size_t)row * K + k0 + kq * kper;
#pragma unroll
                for (int jj = 0; jj < kper; jj += 4) {
                    float4 av = *(const float4*)(ap + jj);
                    As[kq * kper + jj + 0][lm] = av.x;
                    As[kq * kper + jj + 1][lm] = av.y;
                    As[kq * kper + jj + 2][lm] = av.z;
                    As[kq * kper + jj + 3][lm] = av.w;
                }
            } else {
#pragma unroll
                for (int jj = 0; jj < kper; jj++) As[kq * kper + jj][lm] = 0.f;
            }
        }
        // W tile (straight copy): Ws[k][c] = W[k0+k][c]
        {
            constexpr int nf4 = BK * BN / 4;
            constexpr int per = nf4 / (BN * 2);  // 4
#pragma unroll
            for (int ii = 0; ii < per; ii++) {
                int f = t + ii * (BN * 2);
                int kk = (f * 4) / BN;
                int cc = (f * 4) % BN;
                *(float4*)&Ws[kk][cc] = *(const float4*)(W + (size_t)(k0 + kk) * BN + cc);
            }
        }
        __syncthreads();
#pragma unroll
        for (int k = 0; k < BK; k++) {
            float4 a = *(const float4*)&As[k][ty * 4];
            float4 b0 = *(const float4*)&Ws[k][tx * 8];
            float4 b1 = *(const float4*)&Ws[k][tx * 8 + 4];
            float av[4] = {a.x, a.y, a.z, a.w};
            float bv[8] = {b0.x, b0.y, b0.z, b0.w, b1.x, b1.y, b1.z, b1.w};
#pragma unroll
            for (int i = 0; i < 4; i++)
#pragma unroll
                for (int j = 0; j < 8; j++) acc[i][j] += av[i] * bv[j];
        }
        __syncthreads();
    }
#pragma unroll
    for (int i = 0; i < 4; i++) {
        int row = row0 + ty * 4 + i;
        if (row < n) {
            float4 o0 = {acc[i][0], acc[i][1], acc[i][2], acc[i][3]};
            float4 o1 = {acc[i][4], acc[i][5], acc[i][6], acc[i][7]};
            *(float4*)(C + (size_t)row * BN + tx * 8) = o0;
            *(float4*)(C + (size_t)row * BN + tx * 8 + 4) = o1;
        }
    }
}

// Aggregation: out_i = relu( dinv_i^2 * t_i + sum_{p} wgt[p] * t[col[p]] + bias ).
// One wave per node; lane handles VEC consecutive channels (channels = 64*VEC).
template <int VEC>
__global__ __launch_bounds__(256) void k_agg(const float* __restrict__ t,
                                             const int* __restrict__ rowptr,
                                             const int* __restrict__ col,
                                             const float* __restrict__ wgt,
                                             const float* __restrict__ dinv,
                                             const float* __restrict__ bias,
                                             float* __restrict__ out, int n) {
    int w = (int)((blockIdx.x * (unsigned)blockDim.x + threadIdx.x) >> 6);
    int lane = threadIdx.x & 63;
    if (w >= n) return;
    constexpr int CH = VEC * 64;
    float di = dinv[w];
    float sw = di * di;
    float acc[VEC];
#pragma unroll
    for (int v = 0; v < VEC; v++) acc[v] = t[(size_t)w * CH + lane * VEC + v] * sw;
    int p = rowptr[w], pe = rowptr[w + 1];
    for (; p < pe; p++) {
        int j = col[p];
        float ww = wgt[p];
#pragma unroll
        for (int v = 0; v < VEC; v++) acc[v] += ww * t[(size_t)j * CH + lane * VEC + v];
    }
#pragma unroll
    for (int v = 0; v < VEC; v++) {
        float val = acc[v] + bias[lane * VEC + v];
        out[(size_t)w * CH + lane * VEC + v] = fmaxf(val, 0.f);
    }
}

__global__ __launch_bounds__(256) void k_pool(const float* __restrict__ h,
                                              const int* __restrict__ batch,
                                              float* __restrict__ psum,
                                              int* __restrict__ pcnt, int n) {
    int w = (int)((blockIdx.x * (unsigned)blockDim.x + threadIdx.x) >> 6);
    int lane = threadIdx.x & 63;
    if (w >= n) return;
    int b = batch[w];
    atomicAdd(&psum[b * 64 + lane], h[(size_t)w * 64 + lane]);
    if (lane == 0) atomicAdd(&pcnt[b], 1);
}

__global__ __launch_bounds__(64) void k_mlp(const float* __restrict__ psum,
                                            const int* __restrict__ pcnt,
                                            const float* __restrict__ demo,
                                            const float* __restrict__ Wf1,
                                            const float* __restrict__ bf1,
                                            const float* __restrict__ Wf2,
                                            const float* __restrict__ bf2,
                                            const float* __restrict__ Wf3,
                                            const float* __restrict__ bf3,
                                            float* __restrict__ out, int G) {
    int g = blockIdx.x;
    int tid = threadIdx.x;
    __shared__ float zin[72];
    __shared__ float z1[64];
    __shared__ float z2[32];
    float inv = 1.0f / fmaxf((float)pcnt[g], 1.0f);
    zin[tid] = psum[g * 64 + tid] * inv;
    if (tid < 8) zin[64 + tid] = demo[g * 8 + tid];
    __syncthreads();
    float a = bf1[tid];
    for (int k = 0; k < 72; k++) a += zin[k] * Wf1[k * 64 + tid];
    z1[tid] = fmaxf(a, 0.f);
    __syncthreads();
    if (tid < 32) {
        float a2 = bf2[tid];
        for (int k = 0; k < 64; k++) a2 += z1[k] * Wf2[k * 32 + tid];
        z2[tid] = fmaxf(a2, 0.f);
    }
    __syncthreads();
    if (tid < 2) {
        float a3 = bf3[tid];
        for (int k = 0; k < 32; k++) a3 += z2[k] * Wf3[k * 2 + tid];
        out[g * 2 + tid] = a3;
    }
}

extern "C" void kernel_launch(void* const* d_in, const int* in_sizes, int n_in,
                              void* d_out, int out_size, void* d_ws, size_t ws_size,
                              hipStream_t stream) {
    const float* x    = (const float*)d_in[0];
    const int*   ei   = (const int*)d_in[1];
    const int*   batch= (const int*)d_in[2];
    const float* demo = (const float*)d_in[3];
    const float* W1   = (const float*)d_in[4];
    const float* b1   = (const float*)d_in[5];
    const float* W2   = (const float*)d_in[6];
    const float* b2   = (const float*)d_in[7];
    const float* W3   = (const float*)d_in[8];
    const float* b3   = (const float*)d_in[9];
    const float* Wf1  = (const float*)d_in[10];
    const float* bf1  = (const float*)d_in[11];
    const float* Wf2  = (const float*)d_in[12];
    const float* bf2  = (const float*)d_in[13];
    const float* Wf3  = (const float*)d_in[14];
    const float* bf3  = (const float*)d_in[15];
    float* out = (float*)d_out;

    const int n = in_sizes[0] / 128;  // 50000
    const int E = in_sizes[1] / 2;    // 600000
    const int G = in_sizes[3] / 8;    // 100

    char* ws = (char*)d_ws;
    auto alloc = [&](size_t bytes) {
        char* p = ws;
        ws += (bytes + 255) & ~(size_t)255;
        return p;
    };
    int*   cnt    = (int*)alloc((size_t)n * 4);
    int*   fill   = (int*)alloc((size_t)n * 4);
    float* dinv   = (float*)alloc((size_t)n * 4);
    int*   rowptr = (int*)alloc((size_t)(n + 1) * 4);
    int*   col    = (int*)alloc((size_t)E * 4);
    float* wgt    = (float*)alloc((size_t)E * 4);
    float* bufA   = (float*)alloc((size_t)n * 128 * 4);
    float* bufB   = (float*)alloc((size_t)n * 128 * 4);
    float* psum   = (float*)alloc((size_t)G * 64 * 4);
    int*   pcnt   = (int*)alloc((size_t)G * 4);

    const int* srcv = ei;
    const int* dstv = ei + E;

    hipMemsetAsync(cnt, 0, (size_t)n * 4, stream);
    hipMemsetAsync(fill, 0, (size_t)n * 4, stream);
    hipMemsetAsync(psum, 0, (size_t)G * 64 * 4, stream);
    hipMemsetAsync(pcnt, 0, (size_t)G * 4, stream);

    k_deg<<<(E + 255) / 256, 256, 0, stream>>>(dstv, cnt, E);
    k_dinv<<<(n + 255) / 256, 256, 0, stream>>>(cnt, dinv, n);
    k_scan<<<1, 1024, 0, stream>>>(cnt, rowptr, n);
    k_csr<<<(E + 255) / 256, 256, 0, stream>>>(srcv, dstv, rowptr, fill, dinv, col, wgt, E);

    int gemm_blocks = (n + 63) / 64;
    int agg_blocks = (int)(((size_t)n * 64 + 255) / 256);

    // Layer 1: t = x@W1 ; h1 = relu(agg(t) + b1)
    k_gemm<128><<<gemm_blocks, 256, 0, stream>>>(x, W1, bufA, n);
    k_agg<2><<<agg_blocks, 256, 0, stream>>>(bufA, rowptr, col, wgt, dinv, b1, bufB, n);
    // Layer 2
    k_gemm<128><<<gemm_blocks, 256, 0, stream>>>(bufB, W2, bufA, n);
    k_agg<2><<<agg_blocks, 256, 0, stream>>>(bufA, rowptr, col, wgt, dinv, b2, bufB, n);
    // Layer 3 (128 -> 64): GEMM first so aggregation runs on 64 channels
    k_gemm<64><<<gemm_blocks, 128, 0, stream>>>(bufB, W3, bufA, n);
    k_agg<1><<<agg_blocks, 256, 0, stream>>>(bufA, rowptr, col, wgt, dinv, b3, bufB, n);

    k_pool<<<agg_blocks, 256, 0, stream>>>(bufB, batch, psum, pcnt, n);
    k_mlp<<<G, 64, 0, stream>>>(psum, pcnt, demo, Wf1, bf1, Wf2, bf2, Wf3, bf3, out, G);
}

// Round 2
// 520.222 us; speedup vs baseline: 1.3699x; 1.3699x over previous
//
#include <hip/hip_runtime.h>

// ---------------------------------------------------------------------------
// ROIAwareGCN: 3x GCNConv (CSR-gather, no atomics in hot path) + mean-pool + MLP
// All fp32. CSR built on-device every launch (same work per call).
// R1: replaced atomic mean-pool (250us, atomic-serialization-bound) with
//     segmented reduction exploiting sorted `batch` (graphs are contiguous).
// ---------------------------------------------------------------------------

__global__ void k_deg(const int* __restrict__ dst, int* __restrict__ cnt, int E) {
    int e = blockIdx.x * blockDim.x + threadIdx.x;
    if (e < E) atomicAdd(&cnt[dst[e]], 1);
}

__global__ void k_dinv(const int* __restrict__ cnt, float* __restrict__ dinv, int n) {
    int i = blockIdx.x * blockDim.x + threadIdx.x;
    if (i < n) dinv[i] = rsqrtf((float)(cnt[i] + 1));  // +1 for self-loop; deg >= 1 always
}

// Single-block exclusive scan over cnt -> rowptr (n+1 entries).
__global__ __launch_bounds__(1024) void k_scan(const int* __restrict__ cnt,
                                               int* __restrict__ rowptr, int n) {
    __shared__ int wsum[16];
    __shared__ int carry_s;
    int tid = threadIdx.x;
    int lane = tid & 63;
    int wid = tid >> 6;
    if (tid == 0) carry_s = 0;
    __syncthreads();
    for (int base = 0; base < n; base += 4096) {
        int i0 = base + tid * 4;
        int v[4];
#pragma unroll
        for (int j = 0; j < 4; j++) v[j] = (i0 + j < n) ? cnt[i0 + j] : 0;
        int s0 = v[0], s1 = s0 + v[1], s2 = s1 + v[2], s3 = s2 + v[3];
        int ts = s3;
        int sc = ts;
#pragma unroll
        for (int d = 1; d < 64; d <<= 1) {
            int o = __shfl_up(sc, d);
            if (lane >= d) sc += o;
        }
        if (lane == 63) wsum[wid] = sc;
        __syncthreads();
        if (wid == 0) {
            int v2 = (lane < 16) ? wsum[lane] : 0;
            int sc2 = v2;
#pragma unroll
            for (int d = 1; d < 16; d <<= 1) {
                int o = __shfl_up(sc2, d);
                if (lane >= d) sc2 += o;
            }
            if (lane < 16) wsum[lane] = sc2;
        }
        __syncthreads();
        int waveoff = (wid > 0) ? wsum[wid - 1] : 0;
        int throff = carry_s + waveoff + (sc - ts);
#pragma unroll
        for (int j = 0; j < 4; j++) {
            int idx = i0 + j;
            int pre = (j == 0) ? 0 : (j == 1 ? s0 : (j == 2 ? s1 : s2));
            if (idx < n) rowptr[idx] = throff + pre;
        }
        __syncthreads();
        if (tid == 0) carry_s += wsum[15];
        __syncthreads();
    }
    if (threadIdx.x == 0) rowptr[n] = carry_s;
}

__global__ void k_csr(const int* __restrict__ src, const int* __restrict__ dst,
                      const int* __restrict__ rowptr, int* __restrict__ fill,
                      const float* __restrict__ dinv, int* __restrict__ col,
                      float* __restrict__ wgt, int E) {
    int e = blockIdx.x * blockDim.x + threadIdx.x;
    if (e >= E) return;
    int s = src[e], d = dst[e];
    int pos = rowptr[d] + atomicAdd(&fill[d], 1);
    col[pos] = s;
    wgt[pos] = dinv[s] * dinv[d];
}

// Tiled fp32 GEMM: C[n][BN] = A[n][128] @ W[128][BN]. BM=64 rows/block, BK=32.
template <int BN>
__global__ __launch_bounds__(BN * 2) void k_gemm(const float* __restrict__ A,
                                                 const float* __restrict__ W,
                                                 float* __restrict__ C, int n) {
    constexpr int K = 128;
    constexpr int BM = 64;
    constexpr int BK = 32;
    __shared__ float As[BK][BM + 4];
    __shared__ float Ws[BK][BN];
    int t = threadIdx.x;
    int tx = t % (BN / 8);
    int ty = t / (BN / 8);
    int row0 = blockIdx.x * BM;
    float acc[4][8];
#pragma unroll
    for (int i = 0; i < 4; i++)
#pragma unroll
        for (int j = 0; j < 8; j++) acc[i][j] = 0.f;

    for (int k0 = 0; k0 < K; k0 += BK) {
        {
            int lm = t % BM;
            constexpr int nk = (BN * 2) / BM;
            constexpr int kper = BK / nk;
            int kq = t / BM;
            int row = row0 + lm;
            if (row < n) {
                const float* ap = A + (size_t)row * K + k0 + kq * kper;
#pragma unroll
                for (int jj = 0; jj < kper; jj += 4) {
                    float4 av = *(const float4*)(ap + jj);
                    As[kq * kper + jj + 0][lm] = av.x;
                    As[kq * kper + jj + 1][lm] = av.y;
                    As[kq * kper + jj + 2][lm] = av.z;
                    As[kq * kper + jj + 3][lm] = av.w;
                }
            } else {
#pragma unroll
                for (int jj = 0; jj < kper; jj++) As[kq * kper + jj][lm] = 0.f;
            }
        }
        {
            constexpr int nf4 = BK * BN / 4;
            constexpr int per = nf4 / (BN * 2);
#pragma unroll
            for (int ii = 0; ii < per; ii++) {
                int f = t + ii * (BN * 2);
                int kk = (f * 4) / BN;
                int cc = (f * 4) % BN;
                *(float4*)&Ws[kk][cc] = *(const float4*)(W + (size_t)(k0 + kk) * BN + cc);
            }
        }
        __syncthreads();
#pragma unroll
        for (int k = 0; k < BK; k++) {
            float4 a = *(const float4*)&As[k][ty * 4];
            float4 b0 = *(const float4*)&Ws[k][tx * 8];
            float4 b1 = *(const float4*)&Ws[k][tx * 8 + 4];
            float av[4] = {a.x, a.y, a.z, a.w};
            float bv[8] = {b0.x, b0.y, b0.z, b0.w, b1.x, b1.y, b1.z, b1.w};
#pragma unroll
            for (int i = 0; i < 4; i++)
#pragma unroll
                for (int j = 0; j < 8; j++) acc[i][j] += av[i] * bv[j];
        }
        __syncthreads();
    }
#pragma unroll
    for (int i = 0; i < 4; i++) {
        int row = row0 + ty * 4 + i;
        if (row < n) {
            float4 o0 = {acc[i][0], acc[i][1], acc[i][2], acc[i][3]};
            float4 o1 = {acc[i][4], acc[i][5], acc[i][6], acc[i][7]};
            *(float4*)(C + (size_t)row * BN + tx * 8) = o0;
            *(float4*)(C + (size_t)row * BN + tx * 8 + 4) = o1;
        }
    }
}

// Aggregation: out_i = relu( dinv_i^2 * t_i + sum_{p} wgt[p] * t[col[p]] + bias ).
template <int VEC>
__global__ __launch_bounds__(256) void k_agg(const float* __restrict__ t,
                                             const int* __restrict__ rowptr,
                                             const int* __restrict__ col,
                                             const float* __restrict__ wgt,
                                             const float* __restrict__ dinv,
                                             const float* __restrict__ bias,
                                             float* __restrict__ out, int n) {
    int w = (int)((blockIdx.x * (unsigned)blockDim.x + threadIdx.x) >> 6);
    int lane = threadIdx.x & 63;
    if (w >= n) return;
    constexpr int CH = VEC * 64;
    float di = dinv[w];
    float sw = di * di;
    float acc[VEC];
#pragma unroll
    for (int v = 0; v < VEC; v++) acc[v] = t[(size_t)w * CH + lane * VEC + v] * sw;
    int p = rowptr[w], pe = rowptr[w + 1];
    for (; p < pe; p++) {
        int j = col[p];
        float ww = wgt[p];
#pragma unroll
        for (int v = 0; v < VEC; v++) acc[v] += ww * t[(size_t)j * CH + lane * VEC + v];
    }
#pragma unroll
    for (int v = 0; v < VEC; v++) {
        float val = acc[v] + bias[lane * VEC + v];
        out[(size_t)w * CH + lane * VEC + v] = fmaxf(val, 0.f);
    }
}

// ---- segmented mean-pool over sorted batch (no atomics) ----
__global__ void k_gb_init(int* __restrict__ gstart, int G, int n) {
    int i = blockIdx.x * blockDim.x + threadIdx.x;
    if (i <= G) gstart[i] = n;
}

__global__ void k_gb(const int* __restrict__ batch, int* __restrict__ gstart, int n) {
    int i = blockIdx.x * blockDim.x + threadIdx.x;
    if (i >= n) return;
    if (i == 0 || batch[i] != batch[i - 1]) gstart[batch[i]] = i;
}

__global__ void k_gb_fix(int* __restrict__ gstart, int G) {
    // single thread: suffix-min so empty graphs get start == next start
    if (blockIdx.x == 0 && threadIdx.x == 0) {
        for (int g = G - 1; g >= 0; g--)
            if (gstart[g] > gstart[g + 1]) gstart[g] = gstart[g + 1];
    }
}

__global__ __launch_bounds__(256) void k_pool2(const float* __restrict__ h,
                                               const int* __restrict__ gstart,
                                               float* __restrict__ pooled, int G) {
    int g = blockIdx.x;
    int lane = threadIdx.x & 63;
    int wv = threadIdx.x >> 6;
    int s = gstart[g], e = gstart[g + 1];
    float acc = 0.f;
    for (int i = s + wv; i < e; i += 4) acc += h[(size_t)i * 64 + lane];
    __shared__ float red[4][64];
    red[wv][lane] = acc;
    __syncthreads();
    if (wv == 0) {
        float v = red[0][lane] + red[1][lane] + red[2][lane] + red[3][lane];
        float cnt = (float)(e - s);
        pooled[g * 64 + lane] = v / fmaxf(cnt, 1.0f);
    }
}

__global__ __launch_bounds__(64) void k_mlp(const float* __restrict__ pooled,
                                            const float* __restrict__ demo,
                                            const float* __restrict__ Wf1,
                                            const float* __restrict__ bf1,
                                            const float* __restrict__ Wf2,
                                            const float* __restrict__ bf2,
                                            const float* __restrict__ Wf3,
                                            const float* __restrict__ bf3,
                                            float* __restrict__ out, int G) {
    int g = blockIdx.x;
    int tid = threadIdx.x;
    __shared__ float zin[72];
    __shared__ float z1[64];
    __shared__ float z2[32];
    zin[tid] = pooled[g * 64 + tid];
    if (tid < 8) zin[64 + tid] = demo[g * 8 + tid];
    __syncthreads();
    float a = bf1[tid];
    for (int k = 0; k < 72; k++) a += zin[k] * Wf1[k * 64 + tid];
    z1[tid] = fmaxf(a, 0.f);
    __syncthreads();
    if (tid < 32) {
        float a2 = bf2[tid];
        for (int k = 0; k < 64; k++) a2 += z1[k] * Wf2[k * 32 + tid];
        z2[tid] = fmaxf(a2, 0.f);
    }
    __syncthreads();
    if (tid < 2) {
        float a3 = bf3[tid];
        for (int k = 0; k < 32; k++) a3 += z2[k] * Wf3[k * 2 + tid];
        out[g * 2 + tid] = a3;
    }
}

extern "C" void kernel_launch(void* const* d_in, const int* in_sizes, int n_in,
                              void* d_out, int out_size, void* d_ws, size_t ws_size,
                              hipStream_t stream) {
    const float* x    = (const float*)d_in[0];
    const int*   ei   = (const int*)d_in[1];
    const int*   batch= (const int*)d_in[2];
    const float* demo = (const float*)d_in[3];
    const float* W1   = (const float*)d_in[4];
    const float* b1   = (const float*)d_in[5];
    const float* W2   = (const float*)d_in[6];
    const float* b2   = (const float*)d_in[7];
    const float* W3   = (const float*)d_in[8];
    const float* b3   = (const float*)d_in[9];
    const float* Wf1  = (const float*)d_in[10];
    const float* bf1  = (const float*)d_in[11];
    const float* Wf2  = (const float*)d_in[12];
    const float* bf2  = (const float*)d_in[13];
    const float* Wf3  = (const float*)d_in[14];
    const float* bf3  = (const float*)d_in[15];
    float* out = (float*)d_out;

    const int n = in_sizes[0] / 128;  // 50000
    const int E = in_sizes[1] / 2;    // 600000
    const int G = in_sizes[3] / 8;    // 100

    char* ws = (char*)d_ws;
    auto alloc = [&](size_t bytes) {
        char* p = ws;
        ws += (bytes + 255) & ~(size_t)255;
        return p;
    };
    int*   cnt    = (int*)alloc((size_t)n * 4);
    int*   fill   = (int*)alloc((size_t)n * 4);
    float* dinv   = (float*)alloc((size_t)n * 4);
    int*   rowptr = (int*)alloc((size_t)(n + 1) * 4);
    int*   col    = (int*)alloc((size_t)E * 4);
    float* wgt    = (float*)alloc((size_t)E * 4);
    float* bufA   = (float*)alloc((size_t)n * 128 * 4);
    float* bufB   = (float*)alloc((size_t)n * 128 * 4);
    int*   gstart = (int*)alloc((size_t)(G + 1) * 4);
    float* pooled = (float*)alloc((size_t)G * 64 * 4);

    const int* srcv = ei;
    const int* dstv = ei + E;

    hipMemsetAsync(cnt, 0, (size_t)n * 4, stream);
    hipMemsetAsync(fill, 0, (size_t)n * 4, stream);

    k_deg<<<(E + 255) / 256, 256, 0, stream>>>(dstv, cnt, E);
    k_dinv<<<(n + 255) / 256, 256, 0, stream>>>(cnt, dinv, n);
    k_scan<<<1, 1024, 0, stream>>>(cnt, rowptr, n);
    k_csr<<<(E + 255) / 256, 256, 0, stream>>>(srcv, dstv, rowptr, fill, dinv, col, wgt, E);

    // graph boundaries (batch is sorted)
    k_gb_init<<<(G + 256) / 256, 256, 0, stream>>>(gstart, G, n);
    k_gb<<<(n + 255) / 256, 256, 0, stream>>>(batch, gstart, n);
    k_gb_fix<<<1, 64, 0, stream>>>(gstart, G);

    int gemm_blocks = (n + 63) / 64;
    int agg_blocks = (int)(((size_t)n * 64 + 255) / 256);

    // Layer 1: t = x@W1 ; h1 = relu(agg(t) + b1)
    k_gemm<128><<<gemm_blocks, 256, 0, stream>>>(x, W1, bufA, n);
    k_agg<2><<<agg_blocks, 256, 0, stream>>>(bufA, rowptr, col, wgt, dinv, b1, bufB, n);
    // Layer 2
    k_gemm<128><<<gemm_blocks, 256, 0, stream>>>(bufB, W2, bufA, n);
    k_agg<2><<<agg_blocks, 256, 0, stream>>>(bufA, rowptr, col, wgt, dinv, b2, bufB, n);
    // Layer 3 (128 -> 64): GEMM first so aggregation runs on 64 channels
    k_gemm<64><<<gemm_blocks, 128, 0, stream>>>(bufB, W3, bufA, n);
    k_agg<1><<<agg_blocks, 256, 0, stream>>>(bufA, rowptr, col, wgt, dinv, b3, bufB, n);

    k_pool2<<<G, 256, 0, stream>>>(bufB, gstart, pooled, G);
    k_mlp<<<G, 64, 0, stream>>>(pooled, demo, Wf1, bf1, Wf2, bf2, Wf3, bf3, out, G);
}

// Round 3
// 388.970 us; speedup vs baseline: 1.8322x; 1.3374x over previous
//
#include <hip/hip_runtime.h>

// ---------------------------------------------------------------------------
// ROIAwareGCN: 3x GCNConv + mean-pool + MLP.
// R1: atomic pool -> segmented reduction over sorted batch (250us -> ~10us).
// R2: fp32 VALU GEMM (~100us each) -> split-bf16 MFMA GEMM (hi/lo, 3 mfma per
//     K-chunk, error ~1e-4 rel), no LDS / no barriers, W pre-packed into MFMA
//     fragment layout. GEMM writes t in bf16 -> agg gather traffic halved.
//     agg edge loop unrolled x4 for gather ILP (was latency-bound, VALU 13%).
// ---------------------------------------------------------------------------

typedef __bf16 bf16x8 __attribute__((ext_vector_type(8)));
typedef float f32x4 __attribute__((ext_vector_type(4)));

__device__ __forceinline__ float bflo(unsigned u) { return __uint_as_float(u << 16); }
__device__ __forceinline__ float bfhi(unsigned u) { return __uint_as_float(u & 0xffff0000u); }

// ---------------- CSR build ----------------
__global__ void k_deg(const int* __restrict__ dst, int* __restrict__ cnt, int E) {
    int e = blockIdx.x * blockDim.x + threadIdx.x;
    if (e < E) atomicAdd(&cnt[dst[e]], 1);
}

__global__ void k_dinv(const int* __restrict__ cnt, float* __restrict__ dinv, int n) {
    int i = blockIdx.x * blockDim.x + threadIdx.x;
    if (i < n) dinv[i] = rsqrtf((float)(cnt[i] + 1));  // +1 self-loop
}

__global__ __launch_bounds__(1024) void k_scan(const int* __restrict__ cnt,
                                               int* __restrict__ rowptr, int n) {
    __shared__ int wsum[16];
    __shared__ int carry_s;
    int tid = threadIdx.x;
    int lane = tid & 63;
    int wid = tid >> 6;
    if (tid == 0) carry_s = 0;
    __syncthreads();
    for (int base = 0; base < n; base += 4096) {
        int i0 = base + tid * 4;
        int v[4];
#pragma unroll
        for (int j = 0; j < 4; j++) v[j] = (i0 + j < n) ? cnt[i0 + j] : 0;
        int s0 = v[0], s1 = s0 + v[1], s2 = s1 + v[2], s3 = s2 + v[3];
        int ts = s3;
        int sc = ts;
#pragma unroll
        for (int d = 1; d < 64; d <<= 1) {
            int o = __shfl_up(sc, d);
            if (lane >= d) sc += o;
        }
        if (lane == 63) wsum[wid] = sc;
        __syncthreads();
        if (wid == 0) {
            int v2 = (lane < 16) ? wsum[lane] : 0;
            int sc2 = v2;
#pragma unroll
            for (int d = 1; d < 16; d <<= 1) {
                int o = __shfl_up(sc2, d);
                if (lane >= d) sc2 += o;
            }
            if (lane < 16) wsum[lane] = sc2;
        }
        __syncthreads();
        int waveoff = (wid > 0) ? wsum[wid - 1] : 0;
        int throff = carry_s + waveoff + (sc - ts);
#pragma unroll
        for (int j = 0; j < 4; j++) {
            int idx = i0 + j;
            int pre = (j == 0) ? 0 : (j == 1 ? s0 : (j == 2 ? s1 : s2));
            if (idx < n) rowptr[idx] = throff + pre;
        }
        __syncthreads();
        if (tid == 0) carry_s += wsum[15];
        __syncthreads();
    }
    if (threadIdx.x == 0) rowptr[n] = carry_s;
}

__global__ void k_csr(const int* __restrict__ src, const int* __restrict__ dst,
                      const int* __restrict__ rowptr, int* __restrict__ fill,
                      const float* __restrict__ dinv, int* __restrict__ col,
                      float* __restrict__ wgt, int E) {
    int e = blockIdx.x * blockDim.x + threadIdx.x;
    if (e >= E) return;
    int s = src[e], d = dst[e];
    int pos = rowptr[d] + atomicAdd(&fill[d], 1);
    col[pos] = s;
    wgt[pos] = dinv[s] * dinv[d];
}

// ---------------- W pre-pack into MFMA B-fragment layout ----------------
// Frag for (tile t, chunk c, lane l, j): B[k = c*32 + (l>>4)*8 + j][n = t*16 + (l&15)]
// Packed linear index: ((t*4 + c)*64 + l)*8 + j   (hi and lo buffers)
__global__ void k_wpack(const float* __restrict__ W, __bf16* __restrict__ hi,
                        __bf16* __restrict__ lo, int N) {
    int b = blockIdx.x;  // t*4 + c
    int l = threadIdx.x; // 0..63
    int t = b >> 2, c = b & 3;
    int k0 = c * 32 + (l >> 4) * 8;
    int ncol = t * 16 + (l & 15);
    size_t base = ((size_t)b * 64 + l) * 8;
#pragma unroll
    for (int j = 0; j < 8; j++) {
        float v = W[(size_t)(k0 + j) * N + ncol];
        __bf16 h = (__bf16)v;
        hi[base + j] = h;
        lo[base + j] = (__bf16)(v - (float)h);
    }
}

// ---------------- split-bf16 MFMA GEMM: Cbf[n][NT*16] = A[n][128] @ W ----------------
// One wave per 16 rows. A-frags direct from global (lane: 32B contiguous),
// B-frags from packed buffers (coalesced dwordx4, L2-hot). No LDS, no barriers.
template <int NT>
__global__ __launch_bounds__(256) void k_gemm_mfma(const float* __restrict__ A,
                                                   const __bf16* __restrict__ Wp_hi,
                                                   const __bf16* __restrict__ Wp_lo,
                                                   __bf16* __restrict__ Cbf, int n) {
    constexpr int N = NT * 16;
    int wave = (int)((blockIdx.x * 256u + threadIdx.x) >> 6);
    int lane = threadIdx.x & 63;
    int row0 = wave * 16;
    if (row0 >= n) return;
    int m = lane & 15;
    int q = lane >> 4;
    int row = row0 + m;
    if (row >= n) row = n - 1;  // clamp; affected output rows are store-guarded
    const float* ap = A + (size_t)row * 128 + q * 8;
    bf16x8 ahi[4], alo[4];
#pragma unroll
    for (int c = 0; c < 4; c++) {
        float4 v0 = *(const float4*)(ap + c * 32);
        float4 v1 = *(const float4*)(ap + c * 32 + 4);
        float vv[8] = {v0.x, v0.y, v0.z, v0.w, v1.x, v1.y, v1.z, v1.w};
#pragma unroll
        for (int j = 0; j < 8; j++) {
            __bf16 h = (__bf16)vv[j];
            ahi[c][j] = h;
            alo[c][j] = (__bf16)(vv[j] - (float)h);
        }
    }
#pragma unroll
    for (int t = 0; t < NT; t++) {
        f32x4 acc = {0.f, 0.f, 0.f, 0.f};
#pragma unroll
        for (int c = 0; c < 4; c++) {
            size_t off = ((size_t)(t * 4 + c) * 64 + lane) * 8;
            bf16x8 bh = *(const bf16x8*)(Wp_hi + off);
            bf16x8 bl = *(const bf16x8*)(Wp_lo + off);
            acc = __builtin_amdgcn_mfma_f32_16x16x32_bf16(ahi[c], bh, acc, 0, 0, 0);
            acc = __builtin_amdgcn_mfma_f32_16x16x32_bf16(alo[c], bh, acc, 0, 0, 0);
            acc = __builtin_amdgcn_mfma_f32_16x16x32_bf16(ahi[c], bl, acc, 0, 0, 0);
        }
        int colx = t * 16 + m;
#pragma unroll
        for (int r = 0; r < 4; r++) {
            int orow = row0 + q * 4 + r;
            if (orow < n) Cbf[(size_t)orow * N + colx] = (__bf16)acc[r];
        }
    }
}

// ---------------- aggregation (gather, bf16 t, fp32 accumulate) ----------------
// out_i = relu( dinv_i^2 * t_i + sum_p wgt[p] * t[col[p]] + bias )
__global__ __launch_bounds__(256) void k_agg128(const unsigned int* __restrict__ t32,
                                                const int* __restrict__ rowptr,
                                                const int* __restrict__ col,
                                                const float* __restrict__ wgt,
                                                const float* __restrict__ dinv,
                                                const float* __restrict__ bias,
                                                float* __restrict__ out, int n) {
    int w = (int)((blockIdx.x * 256u + threadIdx.x) >> 6);
    int lane = threadIdx.x & 63;
    if (w >= n) return;
    float di = dinv[w];
    float sw = di * di;
    unsigned us = t32[(size_t)w * 64 + lane];
    float a0 = sw * bflo(us);
    float a1 = sw * bfhi(us);
    int p = rowptr[w], pe = rowptr[w + 1];
    for (; p + 4 <= pe; p += 4) {
        int j0 = col[p], j1 = col[p + 1], j2 = col[p + 2], j3 = col[p + 3];
        float w0 = wgt[p], w1 = wgt[p + 1], w2 = wgt[p + 2], w3 = wgt[p + 3];
        unsigned u0 = t32[(size_t)j0 * 64 + lane];
        unsigned u1 = t32[(size_t)j1 * 64 + lane];
        unsigned u2 = t32[(size_t)j2 * 64 + lane];
        unsigned u3 = t32[(size_t)j3 * 64 + lane];
        a0 += w0 * bflo(u0); a1 += w0 * bfhi(u0);
        a0 += w1 * bflo(u1); a1 += w1 * bfhi(u1);
        a0 += w2 * bflo(u2); a1 += w2 * bfhi(u2);
        a0 += w3 * bflo(u3); a1 += w3 * bfhi(u3);
    }
    for (; p < pe; p++) {
        int j = col[p];
        float ww = wgt[p];
        unsigned u = t32[(size_t)j * 64 + lane];
        a0 += ww * bflo(u); a1 += ww * bfhi(u);
    }
    float2 o;
    o.x = fmaxf(a0 + bias[lane * 2], 0.f);
    o.y = fmaxf(a1 + bias[lane * 2 + 1], 0.f);
    *(float2*)(out + (size_t)w * 128 + lane * 2) = o;
}

__global__ __launch_bounds__(256) void k_agg64(const unsigned short* __restrict__ t16,
                                               const int* __restrict__ rowptr,
                                               const int* __restrict__ col,
                                               const float* __restrict__ wgt,
                                               const float* __restrict__ dinv,
                                               const float* __restrict__ bias,
                                               float* __restrict__ out, int n) {
    int w = (int)((blockIdx.x * 256u + threadIdx.x) >> 6);
    int lane = threadIdx.x & 63;
    if (w >= n) return;
    float di = dinv[w];
    float sw = di * di;
    float acc = sw * __uint_as_float((unsigned)t16[(size_t)w * 64 + lane] << 16);
    int p = rowptr[w], pe = rowptr[w + 1];
    for (; p + 4 <= pe; p += 4) {
        int j0 = col[p], j1 = col[p + 1], j2 = col[p + 2], j3 = col[p + 3];
        float w0 = wgt[p], w1 = wgt[p + 1], w2 = wgt[p + 2], w3 = wgt[p + 3];
        unsigned u0 = t16[(size_t)j0 * 64 + lane];
        unsigned u1 = t16[(size_t)j1 * 64 + lane];
        unsigned u2 = t16[(size_t)j2 * 64 + lane];
        unsigned u3 = t16[(size_t)j3 * 64 + lane];
        acc += w0 * __uint_as_float(u0 << 16);
        acc += w1 * __uint_as_float(u1 << 16);
        acc += w2 * __uint_as_float(u2 << 16);
        acc += w3 * __uint_as_float(u3 << 16);
    }
    for (; p < pe; p++) {
        int j = col[p];
        acc += wgt[p] * __uint_as_float((unsigned)t16[(size_t)j * 64 + lane] << 16);
    }
    out[(size_t)w * 64 + lane] = fmaxf(acc + bias[lane], 0.f);
}

// ---------------- segmented mean-pool (sorted batch) ----------------
__global__ void k_gb_init(int* __restrict__ gstart, int G, int n) {
    int i = blockIdx.x * blockDim.x + threadIdx.x;
    if (i <= G) gstart[i] = n;
}

__global__ void k_gb(const int* __restrict__ batch, int* __restrict__ gstart, int n) {
    int i = blockIdx.x * blockDim.x + threadIdx.x;
    if (i >= n) return;
    if (i == 0 || batch[i] != batch[i - 1]) gstart[batch[i]] = i;
}

__global__ void k_gb_fix(int* __restrict__ gstart, int G) {
    if (blockIdx.x == 0 && threadIdx.x == 0) {
        for (int g = G - 1; g >= 0; g--)
            if (gstart[g] > gstart[g + 1]) gstart[g] = gstart[g + 1];
    }
}

__global__ __launch_bounds__(256) void k_pool2(const float* __restrict__ h,
                                               const int* __restrict__ gstart,
                                               float* __restrict__ pooled, int G) {
    int g = blockIdx.x;
    int lane = threadIdx.x & 63;
    int wv = threadIdx.x >> 6;
    int s = gstart[g], e = gstart[g + 1];
    float acc = 0.f;
    for (int i = s + wv; i < e; i += 4) acc += h[(size_t)i * 64 + lane];
    __shared__ float red[4][64];
    red[wv][lane] = acc;
    __syncthreads();
    if (wv == 0) {
        float v = red[0][lane] + red[1][lane] + red[2][lane] + red[3][lane];
        float cnt = (float)(e - s);
        pooled[g * 64 + lane] = v / fmaxf(cnt, 1.0f);
    }
}

__global__ __launch_bounds__(64) void k_mlp(const float* __restrict__ pooled,
                                            const float* __restrict__ demo,
                                            const float* __restrict__ Wf1,
                                            const float* __restrict__ bf1,
                                            const float* __restrict__ Wf2,
                                            const float* __restrict__ bf2,
                                            const float* __restrict__ Wf3,
                                            const float* __restrict__ bf3,
                                            float* __restrict__ out, int G) {
    int g = blockIdx.x;
    int tid = threadIdx.x;
    __shared__ float zin[72];
    __shared__ float z1[64];
    __shared__ float z2[32];
    zin[tid] = pooled[g * 64 + tid];
    if (tid < 8) zin[64 + tid] = demo[g * 8 + tid];
    __syncthreads();
    float a = bf1[tid];
    for (int k = 0; k < 72; k++) a += zin[k] * Wf1[k * 64 + tid];
    z1[tid] = fmaxf(a, 0.f);
    __syncthreads();
    if (tid < 32) {
        float a2 = bf2[tid];
        for (int k = 0; k < 64; k++) a2 += z1[k] * Wf2[k * 32 + tid];
        z2[tid] = fmaxf(a2, 0.f);
    }
    __syncthreads();
    if (tid < 2) {
        float a3 = bf3[tid];
        for (int k = 0; k < 32; k++) a3 += z2[k] * Wf3[k * 2 + tid];
        out[g * 2 + tid] = a3;
    }
}

extern "C" void kernel_launch(void* const* d_in, const int* in_sizes, int n_in,
                              void* d_out, int out_size, void* d_ws, size_t ws_size,
                              hipStream_t stream) {
    const float* x    = (const float*)d_in[0];
    const int*   ei   = (const int*)d_in[1];
    const int*   batch= (const int*)d_in[2];
    const float* demo = (const float*)d_in[3];
    const float* W1   = (const float*)d_in[4];
    const float* b1   = (const float*)d_in[5];
    const float* W2   = (const float*)d_in[6];
    const float* b2   = (const float*)d_in[7];
    const float* W3   = (const float*)d_in[8];
    const float* b3   = (const float*)d_in[9];
    const float* Wf1  = (const float*)d_in[10];
    const float* bf1  = (const float*)d_in[11];
    const float* Wf2  = (const float*)d_in[12];
    const float* bf2  = (const float*)d_in[13];
    const float* Wf3  = (const float*)d_in[14];
    const float* bf3  = (const float*)d_in[15];
    float* out = (float*)d_out;

    const int n = in_sizes[0] / 128;  // 50000
    const int E = in_sizes[1] / 2;    // 600000
    const int G = in_sizes[3] / 8;    // 100

    char* ws = (char*)d_ws;
    auto alloc = [&](size_t bytes) {
        char* p = ws;
        ws += (bytes + 255) & ~(size_t)255;
        return p;
    };
    int*    cnt    = (int*)alloc((size_t)n * 4);
    int*    fill   = (int*)alloc((size_t)n * 4);
    float*  dinv   = (float*)alloc((size_t)n * 4);
    int*    rowptr = (int*)alloc((size_t)(n + 1) * 4);
    int*    col    = (int*)alloc((size_t)E * 4);
    float*  wgt    = (float*)alloc((size_t)E * 4);
    __bf16* tbf    = (__bf16*)alloc((size_t)n * 128 * 2);  // GEMM out (bf16), layers 1/2
    float*  hbuf   = (float*)alloc((size_t)n * 128 * 4);   // agg out (fp32)
    __bf16* t3bf   = (__bf16*)alloc((size_t)n * 64 * 2);   // GEMM3 out
    float*  h3     = (float*)alloc((size_t)n * 64 * 4);    // agg3 out
    __bf16* Wp1h   = (__bf16*)alloc(128 * 128 * 2);
    __bf16* Wp1l   = (__bf16*)alloc(128 * 128 * 2);
    __bf16* Wp2h   = (__bf16*)alloc(128 * 128 * 2);
    __bf16* Wp2l   = (__bf16*)alloc(128 * 128 * 2);
    __bf16* Wp3h   = (__bf16*)alloc(128 * 64 * 2);
    __bf16* Wp3l   = (__bf16*)alloc(128 * 64 * 2);
    int*    gstart = (int*)alloc((size_t)(G + 1) * 4);
    float*  pooled = (float*)alloc((size_t)G * 64 * 4);

    const int* srcv = ei;
    const int* dstv = ei + E;

    hipMemsetAsync(cnt, 0, (size_t)n * 4, stream);
    hipMemsetAsync(fill, 0, (size_t)n * 4, stream);

    // CSR + norm
    k_deg<<<(E + 255) / 256, 256, 0, stream>>>(dstv, cnt, E);
    k_dinv<<<(n + 255) / 256, 256, 0, stream>>>(cnt, dinv, n);
    k_scan<<<1, 1024, 0, stream>>>(cnt, rowptr, n);
    k_csr<<<(E + 255) / 256, 256, 0, stream>>>(srcv, dstv, rowptr, fill, dinv, col, wgt, E);

    // graph boundaries
    k_gb_init<<<(G + 256) / 256, 256, 0, stream>>>(gstart, G, n);
    k_gb<<<(n + 255) / 256, 256, 0, stream>>>(batch, gstart, n);
    k_gb_fix<<<1, 64, 0, stream>>>(gstart, G);

    // pack weights into MFMA fragment layout (hi/lo split)
    k_wpack<<<32, 64, 0, stream>>>(W1, Wp1h, Wp1l, 128);
    k_wpack<<<32, 64, 0, stream>>>(W2, Wp2h, Wp2l, 128);
    k_wpack<<<16, 64, 0, stream>>>(W3, Wp3h, Wp3l, 64);

    int waves = (n + 15) / 16;
    int gemm_blocks = (waves + 3) / 4;
    int agg_blocks = (int)(((size_t)n * 64 + 255) / 256);

    // Layer 1
    k_gemm_mfma<8><<<gemm_blocks, 256, 0, stream>>>(x, Wp1h, Wp1l, tbf, n);
    k_agg128<<<agg_blocks, 256, 0, stream>>>((const unsigned int*)tbf, rowptr, col, wgt,
                                             dinv, b1, hbuf, n);
    // Layer 2
    k_gemm_mfma<8><<<gemm_blocks, 256, 0, stream>>>(hbuf, Wp2h, Wp2l, tbf, n);
    k_agg128<<<agg_blocks, 256, 0, stream>>>((const unsigned int*)tbf, rowptr, col, wgt,
                                             dinv, b2, hbuf, n);
    // Layer 3 (128 -> 64)
    k_gemm_mfma<4><<<gemm_blocks, 256, 0, stream>>>(hbuf, Wp3h, Wp3l, t3bf, n);
    k_agg64<<<agg_blocks, 256, 0, stream>>>((const unsigned short*)t3bf, rowptr, col, wgt,
                                            dinv, b3, h3, n);

    k_pool2<<<G, 256, 0, stream>>>(h3, gstart, pooled, G);
    k_mlp<<<G, 64, 0, stream>>>(pooled, demo, Wf1, bf1, Wf2, bf2, Wf3, bf3, out, G);
}

// Round 4
// 351.773 us; speedup vs baseline: 2.0260x; 1.1057x over previous
//
#include <hip/hip_runtime.h>

// ---------------------------------------------------------------------------
// ROIAwareGCN: 3x GCNConv + mean-pool + MLP.
// R1: atomic pool -> segmented reduction over sorted batch.
// R2: split-bf16 MFMA GEMM (no LDS), bf16 t, 4-deep gather ILP.
// R3: CSR rows padded to 4 (aligned int4/float4 col/wgt, dummy wgt=0),
//     8-deep gather pipeline; h stored bf16 (bf16-A GEMM for layers 2/3);
//     gstart via 101 parallel binary searches (kills 3 kernels incl. the
//     serial suffix-min); dinv fused into scan; wpack fused into csr grid.
//     Dispatches 20 -> 11.
// ---------------------------------------------------------------------------

typedef __bf16 bf16x8 __attribute__((ext_vector_type(8)));
typedef float f32x4 __attribute__((ext_vector_type(4)));

__device__ __forceinline__ float bflo(unsigned u) { return __uint_as_float(u << 16); }
__device__ __forceinline__ float bfhi(unsigned u) { return __uint_as_float(u & 0xffff0000u); }

union BF2 {
    __bf16 h[2];
    unsigned u;
};

// ---------------- fused: degree count + graph-boundary binary search ----------------
__global__ void k_pre(const int* __restrict__ dst, int* __restrict__ cnt,
                      const int* __restrict__ batch, int* __restrict__ gstart,
                      int E, int n, int G, int EB) {
    int b = blockIdx.x;
    if (b < EB) {
        int e = b * 256 + threadIdx.x;
        if (e < E) atomicAdd(&cnt[dst[e]], 1);
    } else {
        int g = threadIdx.x;
        if (g <= G) {
            int lo = 0, hi = n;
            while (lo < hi) {
                int mid = (lo + hi) >> 1;
                if (batch[mid] < g) lo = mid + 1; else hi = mid;
            }
            gstart[g] = lo;  // lower_bound: first i with batch[i] >= g
        }
    }
}

// ---------------- scan over padded counts -> rowptr; fused dinv ----------------
__global__ __launch_bounds__(1024) void k_scan(const int* __restrict__ cnt,
                                               int* __restrict__ rowptr,
                                               float* __restrict__ dinv, int n) {
    __shared__ int wsum[16];
    __shared__ int carry_s;
    int tid = threadIdx.x;
    int lane = tid & 63;
    int wid = tid >> 6;
    if (tid == 0) carry_s = 0;
    __syncthreads();
    for (int base = 0; base < n; base += 4096) {
        int i0 = base + tid * 4;
        int v[4], pv[4];
#pragma unroll
        for (int j = 0; j < 4; j++) {
            v[j] = (i0 + j < n) ? cnt[i0 + j] : 0;
            pv[j] = (v[j] + 3) & ~3;  // pad row to multiple of 4
            if (i0 + j < n) dinv[i0 + j] = rsqrtf((float)(v[j] + 1));
        }
        int s0 = pv[0], s1 = s0 + pv[1], s2 = s1 + pv[2], s3 = s2 + pv[3];
        int ts = s3;
        int sc = ts;
#pragma unroll
        for (int d = 1; d < 64; d <<= 1) {
            int o = __shfl_up(sc, d);
            if (lane >= d) sc += o;
        }
        if (lane == 63) wsum[wid] = sc;
        __syncthreads();
        if (wid == 0) {
            int v2 = (lane < 16) ? wsum[lane] : 0;
            int sc2 = v2;
#pragma unroll
            for (int d = 1; d < 16; d <<= 1) {
                int o = __shfl_up(sc2, d);
                if (lane >= d) sc2 += o;
            }
            if (lane < 16) wsum[lane] = sc2;
        }
        __syncthreads();
        int waveoff = (wid > 0) ? wsum[wid - 1] : 0;
        int throff = carry_s + waveoff + (sc - ts);
#pragma unroll
        for (int j = 0; j < 4; j++) {
            int idx = i0 + j;
            int pre = (j == 0) ? 0 : (j == 1 ? s0 : (j == 2 ? s1 : s2));
            if (idx < n) rowptr[idx] = throff + pre;
        }
        __syncthreads();
        if (tid == 0) carry_s += wsum[15];
        __syncthreads();
    }
    if (threadIdx.x == 0) rowptr[n] = carry_s;
}

// ---------------- CSR scatter + fused weight packing ----------------
__device__ __forceinline__ void wpack_block(const float* __restrict__ W,
                                            __bf16* __restrict__ hi,
                                            __bf16* __restrict__ lo, int N, int b, int l) {
    int t = b >> 2, c = b & 3;
    int k0 = c * 32 + (l >> 4) * 8;
    int ncol = t * 16 + (l & 15);
    size_t base = ((size_t)b * 64 + l) * 8;
#pragma unroll
    for (int j = 0; j < 8; j++) {
        float v = W[(size_t)(k0 + j) * N + ncol];
        __bf16 h = (__bf16)v;
        hi[base + j] = h;
        lo[base + j] = (__bf16)(v - (float)h);
    }
}

__global__ void k_csr(const int* __restrict__ src, const int* __restrict__ dst,
                      const int* __restrict__ rowptr, int* __restrict__ fill,
                      const float* __restrict__ dinv, int* __restrict__ col,
                      float* __restrict__ wgt, int E, int EB,
                      const float* __restrict__ W1, const float* __restrict__ W2,
                      const float* __restrict__ W3,
                      __bf16* __restrict__ Wp1h, __bf16* __restrict__ Wp1l,
                      __bf16* __restrict__ Wp2h, __bf16* __restrict__ Wp2l,
                      __bf16* __restrict__ Wp3h, __bf16* __restrict__ Wp3l) {
    int b = blockIdx.x;
    if (b < EB) {
        int e = b * 256 + threadIdx.x;
        if (e >= E) return;
        int s = src[e], d = dst[e];
        int pos = rowptr[d] + atomicAdd(&fill[d], 1);
        col[pos] = s;
        wgt[pos] = dinv[s] * dinv[d];
    } else {
        int b64 = (b - EB) * 4 + (threadIdx.x >> 6);  // 0..79
        int l = threadIdx.x & 63;
        if (b64 < 32) wpack_block(W1, Wp1h, Wp1l, 128, b64, l);
        else if (b64 < 64) wpack_block(W2, Wp2h, Wp2l, 128, b64 - 32, l);
        else if (b64 < 80) wpack_block(W3, Wp3h, Wp3l, 64, b64 - 64, l);
    }
}

// ---------------- MFMA GEMMs ----------------
// fp32 A (layer 1): hi/lo split, 3 mfma per K-chunk.
template <int NT>
__global__ __launch_bounds__(256) void k_gemm_f32(const float* __restrict__ A,
                                                  const __bf16* __restrict__ Wp_hi,
                                                  const __bf16* __restrict__ Wp_lo,
                                                  __bf16* __restrict__ Cbf, int n) {
    constexpr int N = NT * 16;
    int wave = (int)((blockIdx.x * 256u + threadIdx.x) >> 6);
    int lane = threadIdx.x & 63;
    int row0 = wave * 16;
    if (row0 >= n) return;
    int m = lane & 15;
    int q = lane >> 4;
    int row = row0 + m;
    if (row >= n) row = n - 1;
    const float* ap = A + (size_t)row * 128 + q * 8;
    bf16x8 ahi[4], alo[4];
#pragma unroll
    for (int c = 0; c < 4; c++) {
        float4 v0 = *(const float4*)(ap + c * 32);
        float4 v1 = *(const float4*)(ap + c * 32 + 4);
        float vv[8] = {v0.x, v0.y, v0.z, v0.w, v1.x, v1.y, v1.z, v1.w};
#pragma unroll
        for (int j = 0; j < 8; j++) {
            __bf16 h = (__bf16)vv[j];
            ahi[c][j] = h;
            alo[c][j] = (__bf16)(vv[j] - (float)h);
        }
    }
#pragma unroll
    for (int t = 0; t < NT; t++) {
        f32x4 acc = {0.f, 0.f, 0.f, 0.f};
#pragma unroll
        for (int c = 0; c < 4; c++) {
            size_t off = ((size_t)(t * 4 + c) * 64 + lane) * 8;
            bf16x8 bh = *(const bf16x8*)(Wp_hi + off);
            bf16x8 bl = *(const bf16x8*)(Wp_lo + off);
            acc = __builtin_amdgcn_mfma_f32_16x16x32_bf16(ahi[c], bh, acc, 0, 0, 0);
            acc = __builtin_amdgcn_mfma_f32_16x16x32_bf16(alo[c], bh, acc, 0, 0, 0);
            acc = __builtin_amdgcn_mfma_f32_16x16x32_bf16(ahi[c], bl, acc, 0, 0, 0);
        }
        int colx = t * 16 + m;
#pragma unroll
        for (int r = 0; r < 4; r++) {
            int orow = row0 + q * 4 + r;
            if (orow < n) Cbf[(size_t)orow * N + colx] = (__bf16)acc[r];
        }
    }
}

// bf16 A (layers 2/3): 2 mfma per K-chunk.
template <int NT>
__global__ __launch_bounds__(256) void k_gemm_bf16(const __bf16* __restrict__ A,
                                                   const __bf16* __restrict__ Wp_hi,
                                                   const __bf16* __restrict__ Wp_lo,
                                                   __bf16* __restrict__ Cbf, int n) {
    constexpr int N = NT * 16;
    int wave = (int)((blockIdx.x * 256u + threadIdx.x) >> 6);
    int lane = threadIdx.x & 63;
    int row0 = wave * 16;
    if (row0 >= n) return;
    int m = lane & 15;
    int q = lane >> 4;
    int row = row0 + m;
    if (row >= n) row = n - 1;
    const __bf16* ap = A + (size_t)row * 128 + q * 8;
    bf16x8 a[4];
#pragma unroll
    for (int c = 0; c < 4; c++) a[c] = *(const bf16x8*)(ap + c * 32);
#pragma unroll
    for (int t = 0; t < NT; t++) {
        f32x4 acc = {0.f, 0.f, 0.f, 0.f};
#pragma unroll
        for (int c = 0; c < 4; c++) {
            size_t off = ((size_t)(t * 4 + c) * 64 + lane) * 8;
            bf16x8 bh = *(const bf16x8*)(Wp_hi + off);
            bf16x8 bl = *(const bf16x8*)(Wp_lo + off);
            acc = __builtin_amdgcn_mfma_f32_16x16x32_bf16(a[c], bh, acc, 0, 0, 0);
            acc = __builtin_amdgcn_mfma_f32_16x16x32_bf16(a[c], bl, acc, 0, 0, 0);
        }
        int colx = t * 16 + m;
#pragma unroll
        for (int r = 0; r < 4; r++) {
            int orow = row0 + q * 4 + r;
            if (orow < n) Cbf[(size_t)orow * N + colx] = (__bf16)acc[r];
        }
    }
}

// ---------------- aggregation (padded CSR: row length % 4 == 0) ----------------
// out_i = relu( dinv_i^2 * t_i + sum_p wgt[p] * t[col[p]] + bias ), bf16 out.
__global__ __launch_bounds__(256) void k_agg128(const unsigned int* __restrict__ t32,
                                                const int* __restrict__ rowptr,
                                                const int* __restrict__ col,
                                                const float* __restrict__ wgt,
                                                const float* __restrict__ dinv,
                                                const float* __restrict__ bias,
                                                unsigned int* __restrict__ out, int n) {
    int w = (int)((blockIdx.x * 256u + threadIdx.x) >> 6);
    int lane = threadIdx.x & 63;
    if (w >= n) return;
    float di = dinv[w];
    float sw = di * di;
    unsigned us = t32[(size_t)w * 64 + lane];
    float a0 = sw * bflo(us);
    float a1 = sw * bfhi(us);
    int p = rowptr[w], pe = rowptr[w + 1];
    for (; p + 8 <= pe; p += 8) {
        int4 c0 = *(const int4*)(col + p);
        int4 c1 = *(const int4*)(col + p + 4);
        float4 w0 = *(const float4*)(wgt + p);
        float4 w1 = *(const float4*)(wgt + p + 4);
        unsigned u0 = t32[((size_t)c0.x << 6) + lane];
        unsigned u1 = t32[((size_t)c0.y << 6) + lane];
        unsigned u2 = t32[((size_t)c0.z << 6) + lane];
        unsigned u3 = t32[((size_t)c0.w << 6) + lane];
        unsigned u4 = t32[((size_t)c1.x << 6) + lane];
        unsigned u5 = t32[((size_t)c1.y << 6) + lane];
        unsigned u6 = t32[((size_t)c1.z << 6) + lane];
        unsigned u7 = t32[((size_t)c1.w << 6) + lane];
        a0 += w0.x * bflo(u0); a1 += w0.x * bfhi(u0);
        a0 += w0.y * bflo(u1); a1 += w0.y * bfhi(u1);
        a0 += w0.z * bflo(u2); a1 += w0.z * bfhi(u2);
        a0 += w0.w * bflo(u3); a1 += w0.w * bfhi(u3);
        a0 += w1.x * bflo(u4); a1 += w1.x * bfhi(u4);
        a0 += w1.y * bflo(u5); a1 += w1.y * bfhi(u5);
        a0 += w1.z * bflo(u6); a1 += w1.z * bfhi(u6);
        a0 += w1.w * bflo(u7); a1 += w1.w * bfhi(u7);
    }
    if (p < pe) {
        int4 c0 = *(const int4*)(col + p);
        float4 w0 = *(const float4*)(wgt + p);
        unsigned u0 = t32[((size_t)c0.x << 6) + lane];
        unsigned u1 = t32[((size_t)c0.y << 6) + lane];
        unsigned u2 = t32[((size_t)c0.z << 6) + lane];
        unsigned u3 = t32[((size_t)c0.w << 6) + lane];
        a0 += w0.x * bflo(u0); a1 += w0.x * bfhi(u0);
        a0 += w0.y * bflo(u1); a1 += w0.y * bfhi(u1);
        a0 += w0.z * bflo(u2); a1 += w0.z * bfhi(u2);
        a0 += w0.w * bflo(u3); a1 += w0.w * bfhi(u3);
    }
    BF2 o;
    o.h[0] = (__bf16)fmaxf(a0 + bias[lane * 2], 0.f);
    o.h[1] = (__bf16)fmaxf(a1 + bias[lane * 2 + 1], 0.f);
    out[(size_t)w * 64 + lane] = o.u;
}

__global__ __launch_bounds__(256) void k_agg64(const unsigned short* __restrict__ t16,
                                               const int* __restrict__ rowptr,
                                               const int* __restrict__ col,
                                               const float* __restrict__ wgt,
                                               const float* __restrict__ dinv,
                                               const float* __restrict__ bias,
                                               float* __restrict__ out, int n) {
    int w = (int)((blockIdx.x * 256u + threadIdx.x) >> 6);
    int lane = threadIdx.x & 63;
    if (w >= n) return;
    float di = dinv[w];
    float sw = di * di;
    float acc = sw * __uint_as_float((unsigned)t16[(size_t)w * 64 + lane] << 16);
    int p = rowptr[w], pe = rowptr[w + 1];
    for (; p + 8 <= pe; p += 8) {
        int4 c0 = *(const int4*)(col + p);
        int4 c1 = *(const int4*)(col + p + 4);
        float4 w0 = *(const float4*)(wgt + p);
        float4 w1 = *(const float4*)(wgt + p + 4);
        unsigned u0 = t16[((size_t)c0.x << 6) + lane];
        unsigned u1 = t16[((size_t)c0.y << 6) + lane];
        unsigned u2 = t16[((size_t)c0.z << 6) + lane];
        unsigned u3 = t16[((size_t)c0.w << 6) + lane];
        unsigned u4 = t16[((size_t)c1.x << 6) + lane];
        unsigned u5 = t16[((size_t)c1.y << 6) + lane];
        unsigned u6 = t16[((size_t)c1.z << 6) + lane];
        unsigned u7 = t16[((size_t)c1.w << 6) + lane];
        acc += w0.x * __uint_as_float(u0 << 16);
        acc += w0.y * __uint_as_float(u1 << 16);
        acc += w0.z * __uint_as_float(u2 << 16);
        acc += w0.w * __uint_as_float(u3 << 16);
        acc += w1.x * __uint_as_float(u4 << 16);
        acc += w1.y * __uint_as_float(u5 << 16);
        acc += w1.z * __uint_as_float(u6 << 16);
        acc += w1.w * __uint_as_float(u7 << 16);
    }
    if (p < pe) {
        int4 c0 = *(const int4*)(col + p);
        float4 w0 = *(const float4*)(wgt + p);
        unsigned u0 = t16[((size_t)c0.x << 6) + lane];
        unsigned u1 = t16[((size_t)c0.y << 6) + lane];
        unsigned u2 = t16[((size_t)c0.z << 6) + lane];
        unsigned u3 = t16[((size_t)c0.w << 6) + lane];
        acc += w0.x * __uint_as_float(u0 << 16);
        acc += w0.y * __uint_as_float(u1 << 16);
        acc += w0.z * __uint_as_float(u2 << 16);
        acc += w0.w * __uint_as_float(u3 << 16);
    }
    out[(size_t)w * 64 + lane] = fmaxf(acc + bias[lane], 0.f);
}

// ---------------- segmented mean-pool + MLP ----------------
__global__ __launch_bounds__(256) void k_pool2(const float* __restrict__ h,
                                               const int* __restrict__ gstart,
                                               float* __restrict__ pooled, int G) {
    int g = blockIdx.x;
    int lane = threadIdx.x & 63;
    int wv = threadIdx.x >> 6;
    int s = gstart[g], e = gstart[g + 1];
    float acc = 0.f;
    for (int i = s + wv; i < e; i += 4) acc += h[(size_t)i * 64 + lane];
    __shared__ float red[4][64];
    red[wv][lane] = acc;
    __syncthreads();
    if (wv == 0) {
        float v = red[0][lane] + red[1][lane] + red[2][lane] + red[3][lane];
        float cnt = (float)(e - s);
        pooled[g * 64 + lane] = v / fmaxf(cnt, 1.0f);
    }
}

__global__ __launch_bounds__(64) void k_mlp(const float* __restrict__ pooled,
                                            const float* __restrict__ demo,
                                            const float* __restrict__ Wf1,
                                            const float* __restrict__ bf1,
                                            const float* __restrict__ Wf2,
                                            const float* __restrict__ bf2,
                                            const float* __restrict__ Wf3,
                                            const float* __restrict__ bf3,
                                            float* __restrict__ out, int G) {
    int g = blockIdx.x;
    int tid = threadIdx.x;
    __shared__ float zin[72];
    __shared__ float z1[64];
    __shared__ float z2[32];
    zin[tid] = pooled[g * 64 + tid];
    if (tid < 8) zin[64 + tid] = demo[g * 8 + tid];
    __syncthreads();
    float a = bf1[tid];
    for (int k = 0; k < 72; k++) a += zin[k] * Wf1[k * 64 + tid];
    z1[tid] = fmaxf(a, 0.f);
    __syncthreads();
    if (tid < 32) {
        float a2 = bf2[tid];
        for (int k = 0; k < 64; k++) a2 += z1[k] * Wf2[k * 32 + tid];
        z2[tid] = fmaxf(a2, 0.f);
    }
    __syncthreads();
    if (tid < 2) {
        float a3 = bf3[tid];
        for (int k = 0; k < 32; k++) a3 += z2[k] * Wf3[k * 2 + tid];
        out[g * 2 + tid] = a3;
    }
}

extern "C" void kernel_launch(void* const* d_in, const int* in_sizes, int n_in,
                              void* d_out, int out_size, void* d_ws, size_t ws_size,
                              hipStream_t stream) {
    const float* x    = (const float*)d_in[0];
    const int*   ei   = (const int*)d_in[1];
    const int*   batch= (const int*)d_in[2];
    const float* demo = (const float*)d_in[3];
    const float* W1   = (const float*)d_in[4];
    const float* b1   = (const float*)d_in[5];
    const float* W2   = (const float*)d_in[6];
    const float* b2   = (const float*)d_in[7];
    const float* W3   = (const float*)d_in[8];
    const float* b3   = (const float*)d_in[9];
    const float* Wf1  = (const float*)d_in[10];
    const float* bf1  = (const float*)d_in[11];
    const float* Wf2  = (const float*)d_in[12];
    const float* bf2  = (const float*)d_in[13];
    const float* Wf3  = (const float*)d_in[14];
    const float* bf3  = (const float*)d_in[15];
    float* out = (float*)d_out;

    const int n = in_sizes[0] / 128;  // 50000
    const int E = in_sizes[1] / 2;    // 600000
    const int G = in_sizes[3] / 8;    // 100
    const int Epad = E + 3 * n;       // worst-case padded CSR size

    char* ws = (char*)d_ws;
    auto alloc = [&](size_t bytes) {
        char* p = ws;
        ws += (bytes + 255) & ~(size_t)255;
        return p;
    };
    int*    cnt    = (int*)alloc((size_t)n * 4);
    int*    fill   = (int*)alloc((size_t)n * 4);
    float*  dinv   = (float*)alloc((size_t)n * 4);
    int*    rowptr = (int*)alloc((size_t)(n + 1) * 4);
    int*    col    = (int*)alloc((size_t)Epad * 4);
    float*  wgt    = (float*)alloc((size_t)Epad * 4);
    __bf16* tbf    = (__bf16*)alloc((size_t)n * 128 * 2);  // GEMM out bf16 (layers 1/2)
    __bf16* hbuf   = (__bf16*)alloc((size_t)n * 128 * 2);  // agg out bf16
    __bf16* t3bf   = (__bf16*)alloc((size_t)n * 64 * 2);   // GEMM3 out
    float*  h3     = (float*)alloc((size_t)n * 64 * 4);    // agg3 out (fp32 for pool)
    __bf16* Wp1h   = (__bf16*)alloc(128 * 128 * 2);
    __bf16* Wp1l   = (__bf16*)alloc(128 * 128 * 2);
    __bf16* Wp2h   = (__bf16*)alloc(128 * 128 * 2);
    __bf16* Wp2l   = (__bf16*)alloc(128 * 128 * 2);
    __bf16* Wp3h   = (__bf16*)alloc(128 * 64 * 2);
    __bf16* Wp3l   = (__bf16*)alloc(128 * 64 * 2);
    int*    gstart = (int*)alloc((size_t)(G + 1) * 4);
    float*  pooled = (float*)alloc((size_t)G * 64 * 4);

    const int* srcv = ei;
    const int* dstv = ei + E;

    // cnt+fill are adjacent allocations: one memset covers both.
    hipMemsetAsync(cnt, 0, (size_t)((char*)fill - (char*)cnt) + (size_t)n * 4, stream);
    // col+wgt adjacent: zero both (dummy CSR slots -> col=0, wgt=0.0f).
    hipMemsetAsync(col, 0, (size_t)((char*)wgt - (char*)col) + (size_t)Epad * 4, stream);

    const int EB = (E + 255) / 256;
    k_pre<<<EB + 1, 256, 0, stream>>>(dstv, cnt, batch, gstart, E, n, G, EB);
    k_scan<<<1, 1024, 0, stream>>>(cnt, rowptr, dinv, n);
    k_csr<<<EB + 20, 256, 0, stream>>>(srcv, dstv, rowptr, fill, dinv, col, wgt, E, EB,
                                       W1, W2, W3, Wp1h, Wp1l, Wp2h, Wp2l, Wp3h, Wp3l);

    int waves = (n + 15) / 16;
    int gemm_blocks = (waves + 3) / 4;
    int agg_blocks = (int)(((size_t)n * 64 + 255) / 256);

    // Layer 1
    k_gemm_f32<8><<<gemm_blocks, 256, 0, stream>>>(x, Wp1h, Wp1l, tbf, n);
    k_agg128<<<agg_blocks, 256, 0, stream>>>((const unsigned int*)tbf, rowptr, col, wgt,
                                             dinv, b1, (unsigned int*)hbuf, n);
    // Layer 2
    k_gemm_bf16<8><<<gemm_blocks, 256, 0, stream>>>(hbuf, Wp2h, Wp2l, tbf, n);
    k_agg128<<<agg_blocks, 256, 0, stream>>>((const unsigned int*)tbf, rowptr, col, wgt,
                                             dinv, b2, (unsigned int*)hbuf, n);
    // Layer 3 (128 -> 64)
    k_gemm_bf16<4><<<gemm_blocks, 256, 0, stream>>>(hbuf, Wp3h, Wp3l, t3bf, n);
    k_agg64<<<agg_blocks, 256, 0, stream>>>((const unsigned short*)t3bf, rowptr, col, wgt,
                                            dinv, b3, h3, n);

    k_pool2<<<G, 256, 0, stream>>>(h3, gstart, pooled, G);
    k_mlp<<<G, 64, 0, stream>>>(pooled, demo, Wf1, bf1, Wf2, bf2, Wf3, bf3, out, G);
}